// Round 2
// baseline (1035.610 us; speedup 1.0000x reference)
//
#include <hip/hip_runtime.h>
#include <stdint.h>
#include <stddef.h>

// CNNLSTM: embed -> conv1d(K=5) -> ReLU -> maxpool4 -> LSTM(T=1023,H=128) -> fc(2)
// Inputs: x int32; ALL float tensors are float32 (reference dtype). Output f32.
// bf16 is used internally (via prep conversion kernels) for the MFMA GEMM stages.

typedef __bf16 bf16;
typedef __bf16 bf16x8 __attribute__((ext_vector_type(8)));
typedef float  f32x4  __attribute__((ext_vector_type(4)));

#define MFMA16(a, b, c) __builtin_amdgcn_mfma_f32_16x16x32_bf16((a), (b), (c), 0, 0, 0)

// ---------------- ws layout (bytes, all 16B aligned) ----------------
#define WS_EMB    0               // emb_bf16 [20000][128]            = 5,120,000
#define WS_BT     5120000         // repacked conv weights [64][640]  =    81,920
#define WS_WIHB   5201920         // w_ih bf16 [512][64]              =    65,536
#define WS_POOLED 5267456         // pooled bf16 [64][1024][64]       = 8,388,608
#define WS_XG     13656064        // xg [64][512][1024] f32 (or bf16 fallback)

// ============ prep A: emb f32 -> bf16 (vectorized, 2.56M elems) ============
__global__ void emb_cvt_k(const float* __restrict__ emb, bf16* __restrict__ embb) {
    int g = blockIdx.x * 256 + threadIdx.x;      // 640,000 threads x 4 elems
    f32x4 v = *(const f32x4*)(emb + g * 4);
    bf16* d = embb + g * 4;
    d[0] = (bf16)v[0]; d[1] = (bf16)v[1]; d[2] = (bf16)v[2]; d[3] = (bf16)v[3];
}

// ============ prep B: conv_w [F][E][K] -> Bt[f][k*128+e] bf16; w_ih -> bf16 ============
__global__ void prep_small_k(const float* __restrict__ conv_w, bf16* __restrict__ bt,
                             const float* __restrict__ w_ih, bf16* __restrict__ w_ihb) {
    int g = blockIdx.x * 256 + threadIdx.x;
    if (g < 64 * 640) {
        int f = g / 640, kk = g - f * 640;
        int k = kk >> 7, e = kk & 127;
        bt[g] = (bf16)conv_w[(f * 128 + e) * 5 + k];
    } else {
        int h = g - 64 * 640;
        if (h < 512 * 64) w_ihb[h] = (bf16)w_ih[h];
    }
}

// ============ kernel 1: embed-gather + conv + ReLU + pool4 ============
// Grid: 2048 = B(64) x 32 tiles of 128 conv positions. 256 threads (4 waves).
// Wave w owns f-range [16w,16w+16). A-tile = 144 token rows of emb_bf16 in LDS.
// C-layout rows = quad*4+reg -> each lane's 4 acc regs are one pool window.
__global__ __launch_bounds__(256, 2) void conv_pool_k(
    const int* __restrict__ x, const bf16* __restrict__ embb,
    const bf16* __restrict__ bt, const float* __restrict__ conv_b,
    bf16* __restrict__ pooled)
{
    __shared__ bf16 T[144 * 136];  // 136 = 128 + 8 pad
    const int b   = blockIdx.x >> 5;
    const int l0  = (blockIdx.x & 31) << 7;
    const int tid = threadIdx.x;
    const int ln  = tid & 63, w = tid >> 6;
    const int l15 = ln & 15, quad = ln >> 4;
    const int f   = w * 16 + l15;

    // persistent B fragments (20 k-chunks x 16B) from repacked Bt
    bf16x8 bfrag[20];
    #pragma unroll
    for (int kc = 0; kc < 20; ++kc) {
        uint4 v = *(const uint4*)(bt + f * 640 + kc * 32 + quad * 8);
        bfrag[kc] = __builtin_bit_cast(bf16x8, v);
    }
    const float cb = conv_b[f];

    // stage 144 token rows (need 132) of emb_bf16 into LDS; 16B/thread/pass
    #pragma unroll
    for (int p = 0; p < 9; ++p) {
        int r = p * 16 + (tid >> 4);
        int cg = tid & 15;
        int token = l0 + r; if (token > 4095) token = 4095;
        int idx = x[b * 4096 + token];
        uint4 v = *(const uint4*)(embb + idx * 128 + cg * 8);
        *(uint4*)(&T[r * 136 + cg * 8]) = v;
    }
    __syncthreads();

    f32x4 acc[8];
    #pragma unroll
    for (int tm = 0; tm < 8; ++tm) acc[tm] = (f32x4){0.f, 0.f, 0.f, 0.f};

    #pragma unroll
    for (int kc = 0; kc < 20; ++kc) {
        const int ktap = kc >> 2;
        const int ecol = (kc & 3) * 32 + quad * 8;
        #pragma unroll
        for (int tm = 0; tm < 8; ++tm) {
            int row = tm * 16 + l15 + ktap;
            bf16x8 a = *(const bf16x8*)(&T[row * 136 + ecol]);
            acc[tm] = MFMA16(a, bfrag[kc], acc[tm]);
        }
    }

    // epilogue: bias + ReLU + pool4 (regs 0..3 = consecutive conv positions)
    #pragma unroll
    for (int tm = 0; tm < 8; ++tm) {
        float mx = fmaxf(fmaxf(acc[tm][0], acc[tm][1]), fmaxf(acc[tm][2], acc[tm][3]));
        mx = fmaxf(mx + cb, 0.f);
        int t = (l0 >> 2) + tm * 4 + quad;
        if (t < 1023) pooled[(b * 1024 + t) * 64 + f] = (bf16)mx;
    }
}

// ============ kernel 2: xg = pooled @ w_ih^T + (b_ih + b_hh) ============
// M = 65536 (m = b*1024 + t, padded), K = 64, N = 512.
// Output layout xg[b][n][t] so C-frag (4 consecutive t) stores contiguously.
__device__ inline void store_xg(float* dst, f32x4 v) { *(f32x4*)dst = v; }
__device__ inline void store_xg(bf16* dst, f32x4 v) {
    dst[0] = (bf16)v[0]; dst[1] = (bf16)v[1]; dst[2] = (bf16)v[2]; dst[3] = (bf16)v[3];
}

template <typename XT>
__global__ __launch_bounds__(256, 2) void xg_gemm_k(
    const bf16* __restrict__ pooled, const bf16* __restrict__ w_ihb,
    const float* __restrict__ b_ih, const float* __restrict__ b_hh,
    XT* __restrict__ xg)
{
    __shared__ bf16 A[256 * 72];  // 72 = 64 + 8 pad
    const int m0  = blockIdx.x * 256;
    const int tid = threadIdx.x;
    const int ln  = tid & 63, w = tid >> 6;
    const int l15 = ln & 15, quad = ln >> 4;

    #pragma unroll
    for (int i = 0; i < 8; ++i) {
        int task = i * 256 + tid;
        int row = task >> 3, ch = task & 7;
        uint4 v = *(const uint4*)(pooled + (m0 + row) * 64 + ch * 8);
        *(uint4*)(&A[row * 72 + ch * 8]) = v;
    }
    __syncthreads();

    bf16x8 afrag[4][2];
    #pragma unroll
    for (int mt = 0; mt < 4; ++mt)
        #pragma unroll
        for (int kc = 0; kc < 2; ++kc)
            afrag[mt][kc] = *(const bf16x8*)(&A[((w * 4 + mt) * 16 + l15) * 72 + kc * 32 + quad * 8]);

    const int b_idx = m0 >> 10;      // batch (constant per WG)
    const int tbase = m0 & 1023;

    for (int nt = 0; nt < 32; ++nt) {
        const int nn = nt * 16 + l15;
        uint4 v0 = *(const uint4*)(w_ihb + nn * 64 + quad * 8);
        uint4 v1 = *(const uint4*)(w_ihb + nn * 64 + 32 + quad * 8);
        bf16x8 bf0 = __builtin_bit_cast(bf16x8, v0);
        bf16x8 bf1 = __builtin_bit_cast(bf16x8, v1);
        const float bias = b_ih[nn] + b_hh[nn];
        #pragma unroll
        for (int mt = 0; mt < 4; ++mt) {
            f32x4 acc = (f32x4){0.f, 0.f, 0.f, 0.f};
            acc = MFMA16(afrag[mt][0], bf0, acc);
            acc = MFMA16(afrag[mt][1], bf1, acc);
            f32x4 sv = {acc[0] + bias, acc[1] + bias, acc[2] + bias, acc[3] + bias};
            int t0 = tbase + (w * 4 + mt) * 16 + quad * 4;
            store_xg(xg + (size_t)(b_idx * 512 + nn) * 1024 + t0, sv);
        }
    }
}

// ============ kernel 3: LSTM recurrence + fc head ============
// 64 WGs (one per batch row) x 512 threads; thread = one gate row with its
// 128 w_hh values (f32) in VGPRs, fully unrolled. h_prev via LDS broadcast.
__device__ inline float sigm_(float v) {
    v = fminf(fmaxf(v, -30.f), 30.f);
    return __builtin_amdgcn_rcpf(1.f + __expf(-v));
}
__device__ inline float tanh_(float v) {
    v = fminf(fmaxf(v, -15.f), 15.f);
    return 1.f - 2.f * __builtin_amdgcn_rcpf(__expf(2.f * v) + 1.f);
}

template <typename XT>
__global__ __launch_bounds__(512, 2) void lstm_fc_k(
    const XT* __restrict__ xg, const float* __restrict__ w_hh,
    const float* __restrict__ fc_w, const float* __restrict__ fc_b,
    float* __restrict__ out)
{
    __shared__ __align__(16) float hp[128];
    __shared__ float gl[512];
    const int b = blockIdx.x;
    const int r = threadIdx.x;   // gate row: 0..127 i, ..f, ..g, ..o

    float w[128];
    {
        const float* wr = w_hh + r * 128;
        #pragma unroll
        for (int c = 0; c < 32; ++c) ((f32x4*)w)[c] = ((const f32x4*)wr)[c];
    }

    if (r < 128) hp[r] = 0.f;
    float cst = 0.f;
    const XT* xrow = xg + (size_t)(b * 512 + r) * 1024;
    float xa = (float)xrow[0];
    __syncthreads();

    for (int s = 0; s < 1023; ++s) {
        float xn = (float)xrow[s + 1];   // index 1023 exists (padded); unused garbage at s=1022 tail
        float acc = xa;
        #pragma unroll
        for (int k = 0; k < 128; k += 4) {
            f32x4 h4 = *(const f32x4*)(&hp[k]);   // all-lane broadcast ds_read_b128
            acc += w[k] * h4[0];
            acc += w[k + 1] * h4[1];
            acc += w[k + 2] * h4[2];
            acc += w[k + 3] * h4[3];
        }
        gl[r] = acc;
        __syncthreads();                 // gl visible; hp reads complete
        if (r < 128) {
            float ig = sigm_(gl[r]);
            float fg = sigm_(gl[128 + r]);
            float gg = tanh_(gl[256 + r]);
            float og = sigm_(gl[384 + r]);
            cst = fg * cst + ig * gg;
            hp[r] = og * tanh_(cst);
        }
        __syncthreads();
        xa = xn;
    }

    // fc: out[b][c] = h_T . fc_w[c] + fc_b[c]
    if (r < 128) {
        int c = r >> 6, j = r & 63;
        float p = hp[2 * j] * fc_w[c * 128 + 2 * j]
                + hp[2 * j + 1] * fc_w[c * 128 + 2 * j + 1];
        #pragma unroll
        for (int off = 32; off > 0; off >>= 1) p += __shfl_down(p, off, 64);
        if (j == 0) out[b * 2 + c] = p + fc_b[c];
    }
}

// ============================ launcher ============================
extern "C" void kernel_launch(void* const* d_in, const int* in_sizes, int n_in,
                              void* d_out, int out_size, void* d_ws, size_t ws_size,
                              hipStream_t stream) {
    const int*   x      = (const int*)d_in[0];
    const float* emb    = (const float*)d_in[1];
    const float* conv_w = (const float*)d_in[2];
    const float* conv_b = (const float*)d_in[3];
    const float* w_ih   = (const float*)d_in[4];
    const float* w_hh   = (const float*)d_in[5];
    const float* b_ih   = (const float*)d_in[6];
    const float* b_hh   = (const float*)d_in[7];
    const float* fc_w   = (const float*)d_in[8];
    const float* fc_b   = (const float*)d_in[9];
    float* out = (float*)d_out;

    char* ws = (char*)d_ws;
    bf16* embb   = (bf16*)(ws + WS_EMB);
    bf16* bt     = (bf16*)(ws + WS_BT);
    bf16* w_ihb  = (bf16*)(ws + WS_WIHB);
    bf16* pooled = (bf16*)(ws + WS_POOLED);
    char* xgp    = ws + WS_XG;

    emb_cvt_k<<<2500, 256, 0, stream>>>(emb, embb);                       // 20000*128/4/256
    prep_small_k<<<288, 256, 0, stream>>>(conv_w, bt, w_ih, w_ihb);       // 40960+32768
    conv_pool_k<<<2048, 256, 0, stream>>>(x, embb, bt, conv_b, pooled);

    const size_t need_f32 = (size_t)WS_XG + (size_t)64 * 512 * 1024 * 4;
    if (ws_size >= need_f32) {
        float* xg = (float*)xgp;
        xg_gemm_k<float><<<256, 256, 0, stream>>>(pooled, w_ihb, b_ih, b_hh, xg);
        lstm_fc_k<float><<<64, 512, 0, stream>>>(xg, w_hh, fc_w, fc_b, out);
    } else {  // bf16 xg fallback if workspace is small (~81 MB total)
        bf16* xg = (bf16*)xgp;
        xg_gemm_k<bf16><<<256, 256, 0, stream>>>(pooled, w_ihb, b_ih, b_hh, xg);
        lstm_fc_k<bf16><<<64, 512, 0, stream>>>(xg, w_hh, fc_w, fc_b, out);
    }
}

// Round 3
// 769.732 us; speedup vs baseline: 1.3454x; 1.3454x over previous
//
#include <hip/hip_runtime.h>
#include <stdint.h>
#include <stddef.h>

// CNNLSTM: embed -> conv1d(K=5) -> ReLU -> maxpool4 -> LSTM(T=1023,H=128) -> fc(2)
// Inputs: x int32; all float tensors float32. Output f32.
// Internals: bf16 MFMA for conv + input-projection GEMMs; f16 dot2 for recurrence.

typedef __bf16 bf16;
typedef __bf16 bf16x8 __attribute__((ext_vector_type(8)));
typedef float  f32x4  __attribute__((ext_vector_type(4)));
typedef _Float16 f16;
typedef f16 f16x2 __attribute__((ext_vector_type(2)));
typedef f16 f16x4 __attribute__((ext_vector_type(4)));
typedef f16 f16x8 __attribute__((ext_vector_type(8)));

#define MFMA16(a, b, c) __builtin_amdgcn_mfma_f32_16x16x32_bf16((a), (b), (c), 0, 0, 0)

#if __has_builtin(__builtin_amdgcn_fdot2)
#define DOT2(a, b, c) __builtin_amdgcn_fdot2((a), (b), (c), false)
#else
#define DOT2(a, b, c) ((c) + (float)(a).x * (float)(b).x + (float)(a).y * (float)(b).y)
#endif

// ---------------- ws layout (bytes) ----------------
// xg (written after conv_pool finishes) overlaps the dead emb_bf16 region.
#define WS_BT     0               // conv weights repacked [64][640] bf16 =    81,920
#define WS_WIHB   81920           // w_ih bf16 [512][64]                  =    65,536
#define WS_WHH    147456          // w_hh f16 [512][128]                  =   131,072
#define WS_POOLED 278528          // pooled bf16 [64][1024][64]           = 8,388,608
#define WS_EMB    8667136         // emb bf16 [20000][128]                = 5,120,000
#define WS_XG     8667136         // xg f16 [64][512][1024]               = 67,108,864
// total = 75,776,000 B

// ============ prep A: emb f32 -> bf16 ============
__global__ void emb_cvt_k(const float* __restrict__ emb, bf16* __restrict__ embb) {
    int g = blockIdx.x * 256 + threadIdx.x;      // 640,000 threads x 4 elems
    f32x4 v = *(const f32x4*)(emb + g * 4);
    bf16* d = embb + g * 4;
    d[0] = (bf16)v[0]; d[1] = (bf16)v[1]; d[2] = (bf16)v[2]; d[3] = (bf16)v[3];
}

// ============ prep B: conv_w repack->bf16; w_ih->bf16; w_hh->f16 ============
__global__ void prep_small_k(const float* __restrict__ conv_w, bf16* __restrict__ bt,
                             const float* __restrict__ w_ih, bf16* __restrict__ w_ihb,
                             const float* __restrict__ w_hh, f16* __restrict__ whh) {
    int g = blockIdx.x * 256 + threadIdx.x;
    if (g < 64 * 640) {
        int f = g / 640, kk = g - f * 640;
        int k = kk >> 7, e = kk & 127;
        bt[g] = (bf16)conv_w[(f * 128 + e) * 5 + k];
    } else if (g < 64 * 640 + 512 * 64) {
        int h = g - 64 * 640;
        w_ihb[h] = (bf16)w_ih[h];
    } else {
        int h = g - (64 * 640 + 512 * 64);
        if (h < 512 * 128) whh[h] = (f16)w_hh[h];
    }
}

// ============ kernel 1: embed-gather + conv + ReLU + pool4 ============
__global__ __launch_bounds__(256, 2) void conv_pool_k(
    const int* __restrict__ x, const bf16* __restrict__ embb,
    const bf16* __restrict__ bt, const float* __restrict__ conv_b,
    bf16* __restrict__ pooled)
{
    __shared__ bf16 T[144 * 136];  // 136 = 128 + 8 pad
    const int b   = blockIdx.x >> 5;
    const int l0  = (blockIdx.x & 31) << 7;
    const int tid = threadIdx.x;
    const int ln  = tid & 63, w = tid >> 6;
    const int l15 = ln & 15, quad = ln >> 4;
    const int f   = w * 16 + l15;

    bf16x8 bfrag[20];
    #pragma unroll
    for (int kc = 0; kc < 20; ++kc) {
        uint4 v = *(const uint4*)(bt + f * 640 + kc * 32 + quad * 8);
        bfrag[kc] = __builtin_bit_cast(bf16x8, v);
    }
    const float cb = conv_b[f];

    #pragma unroll
    for (int p = 0; p < 9; ++p) {
        int r = p * 16 + (tid >> 4);
        int cg = tid & 15;
        int token = l0 + r; if (token > 4095) token = 4095;
        int idx = x[b * 4096 + token];
        uint4 v = *(const uint4*)(embb + idx * 128 + cg * 8);
        *(uint4*)(&T[r * 136 + cg * 8]) = v;
    }
    __syncthreads();

    f32x4 acc[8];
    #pragma unroll
    for (int tm = 0; tm < 8; ++tm) acc[tm] = (f32x4){0.f, 0.f, 0.f, 0.f};

    #pragma unroll
    for (int kc = 0; kc < 20; ++kc) {
        const int ktap = kc >> 2;
        const int ecol = (kc & 3) * 32 + quad * 8;
        #pragma unroll
        for (int tm = 0; tm < 8; ++tm) {
            int row = tm * 16 + l15 + ktap;
            bf16x8 a = *(const bf16x8*)(&T[row * 136 + ecol]);
            acc[tm] = MFMA16(a, bfrag[kc], acc[tm]);
        }
    }

    #pragma unroll
    for (int tm = 0; tm < 8; ++tm) {
        float mx = fmaxf(fmaxf(acc[tm][0], acc[tm][1]), fmaxf(acc[tm][2], acc[tm][3]));
        mx = fmaxf(mx + cb, 0.f);
        int t = (l0 >> 2) + tm * 4 + quad;
        if (t < 1023) pooled[(b * 1024 + t) * 64 + f] = (bf16)mx;
    }
}

// ============ kernel 2: xg = pooled @ w_ih^T + (b_ih + b_hh), f16 out ============
// Output layout xg[b][n][t]: C-frag (4 consecutive t) stores as one 8B f16x4.
__global__ __launch_bounds__(256, 2) void xg_gemm_k(
    const bf16* __restrict__ pooled, const bf16* __restrict__ w_ihb,
    const float* __restrict__ b_ih, const float* __restrict__ b_hh,
    f16* __restrict__ xg)
{
    __shared__ bf16 A[256 * 72];  // 72 = 64 + 8 pad
    const int m0  = blockIdx.x * 256;
    const int tid = threadIdx.x;
    const int ln  = tid & 63, w = tid >> 6;
    const int l15 = ln & 15, quad = ln >> 4;

    #pragma unroll
    for (int i = 0; i < 8; ++i) {
        int task = i * 256 + tid;
        int row = task >> 3, ch = task & 7;
        uint4 v = *(const uint4*)(pooled + (m0 + row) * 64 + ch * 8);
        *(uint4*)(&A[row * 72 + ch * 8]) = v;
    }
    __syncthreads();

    bf16x8 afrag[4][2];
    #pragma unroll
    for (int mt = 0; mt < 4; ++mt)
        #pragma unroll
        for (int kc = 0; kc < 2; ++kc)
            afrag[mt][kc] = *(const bf16x8*)(&A[((w * 4 + mt) * 16 + l15) * 72 + kc * 32 + quad * 8]);

    const int b_idx = m0 >> 10;
    const int tbase = m0 & 1023;

    for (int nt = 0; nt < 32; ++nt) {
        const int nn = nt * 16 + l15;
        uint4 v0 = *(const uint4*)(w_ihb + nn * 64 + quad * 8);
        uint4 v1 = *(const uint4*)(w_ihb + nn * 64 + 32 + quad * 8);
        bf16x8 bf0 = __builtin_bit_cast(bf16x8, v0);
        bf16x8 bf1 = __builtin_bit_cast(bf16x8, v1);
        const float bias = b_ih[nn] + b_hh[nn];
        #pragma unroll
        for (int mt = 0; mt < 4; ++mt) {
            f32x4 acc = (f32x4){0.f, 0.f, 0.f, 0.f};
            acc = MFMA16(afrag[mt][0], bf0, acc);
            acc = MFMA16(afrag[mt][1], bf1, acc);
            int t0 = tbase + (w * 4 + mt) * 16 + quad * 4;
            f16x4 sv = {(f16)(acc[0] + bias), (f16)(acc[1] + bias),
                        (f16)(acc[2] + bias), (f16)(acc[3] + bias)};
            *(f16x4*)(xg + (size_t)(b_idx * 512 + nn) * 1024 + t0) = sv;
        }
    }
}

// ============ kernel 3: LSTM recurrence + fc head ============
// 64 WGs x 256 threads (4 waves). Thread t owns gate rows (t, 256+t):
//   t<128  -> (i, g) of hidden unit t   (kept in registers)
//   t>=128 -> (f, o) of hidden unit t-128 (exchanged via 2 LDS floats)
// h stored as f16[128] (256 B): 16 ds_read_b128 broadcasts feed 256 MACs via dot2.
__device__ inline float sigm_(float v) {
    v = fminf(fmaxf(v, -30.f), 30.f);
    return __builtin_amdgcn_rcpf(1.f + __expf(-v));
}
__device__ inline float tanh_(float v) {
    v = fminf(fmaxf(v, -15.f), 15.f);
    return 1.f - 2.f * __builtin_amdgcn_rcpf(__expf(2.f * v) + 1.f);
}

__global__ __launch_bounds__(256, 1) void lstm_fc_k(
    const f16* __restrict__ xg, const f16* __restrict__ whh,
    const float* __restrict__ fc_w, const float* __restrict__ fc_b,
    float* __restrict__ out)
{
    __shared__ __align__(16) f16 hp[128];
    __shared__ float glf[128], glo[128];
    const int b = blockIdx.x;
    const int t = threadIdx.x;
    const int r0 = t, r1 = 256 + t;

    // 2 weight rows in VGPRs as f16 pairs (128 VGPRs)
    f16x2 w0[64], w1[64];
    #pragma unroll
    for (int c = 0; c < 16; ++c) {
        uint4 v = *(const uint4*)(whh + r0 * 128 + c * 8);
        f16x8 t8 = __builtin_bit_cast(f16x8, v);
        w0[c * 4 + 0] = (f16x2){t8[0], t8[1]}; w0[c * 4 + 1] = (f16x2){t8[2], t8[3]};
        w0[c * 4 + 2] = (f16x2){t8[4], t8[5]}; w0[c * 4 + 3] = (f16x2){t8[6], t8[7]};
    }
    #pragma unroll
    for (int c = 0; c < 16; ++c) {
        uint4 v = *(const uint4*)(whh + r1 * 128 + c * 8);
        f16x8 t8 = __builtin_bit_cast(f16x8, v);
        w1[c * 4 + 0] = (f16x2){t8[0], t8[1]}; w1[c * 4 + 1] = (f16x2){t8[2], t8[3]};
        w1[c * 4 + 2] = (f16x2){t8[4], t8[5]}; w1[c * 4 + 3] = (f16x2){t8[6], t8[7]};
    }

    if (t < 128) hp[t] = (f16)0.f;
    float cst = 0.f;
    const f16* xrow0 = xg + (size_t)(b * 512 + r0) * 1024;
    const f16* xrow1 = xg + (size_t)(b * 512 + r1) * 1024;
    float xa0 = (float)xrow0[0], xa1 = (float)xrow1[0];
    __syncthreads();

    for (int s = 0; s < 1023; ++s) {
        float xn0 = (float)xrow0[s + 1];   // prefetch (index 1023 valid; tail unused)
        float xn1 = (float)xrow1[s + 1];
        float a00 = 0.f, a01 = 0.f, a02 = 0.f, a03 = 0.f;
        float a10 = 0.f, a11 = 0.f, a12 = 0.f, a13 = 0.f;
        #pragma unroll
        for (int c = 0; c < 16; ++c) {
            f16x8 h8 = *(const f16x8*)(&hp[c * 8]);   // broadcast ds_read_b128
            f16x2 p0 = {h8[0], h8[1]}, p1 = {h8[2], h8[3]};
            f16x2 p2 = {h8[4], h8[5]}, p3 = {h8[6], h8[7]};
            a00 = DOT2(w0[c * 4 + 0], p0, a00); a01 = DOT2(w0[c * 4 + 1], p1, a01);
            a02 = DOT2(w0[c * 4 + 2], p2, a02); a03 = DOT2(w0[c * 4 + 3], p3, a03);
            a10 = DOT2(w1[c * 4 + 0], p0, a10); a11 = DOT2(w1[c * 4 + 1], p1, a11);
            a12 = DOT2(w1[c * 4 + 2], p2, a12); a13 = DOT2(w1[c * 4 + 3], p3, a13);
        }
        float acc0 = xa0 + (a00 + a01) + (a02 + a03);   // t<128: i-pre ; t>=128: f-pre
        float acc1 = xa1 + (a10 + a11) + (a12 + a13);   // t<128: g-pre ; t>=128: o-pre
        if (t >= 128) { glf[t - 128] = acc0; glo[t - 128] = acc1; }
        __syncthreads();                 // glf/glo visible; all hp reads complete
        if (t < 128) {
            float ig = sigm_(acc0);
            float gg = tanh_(acc1);
            float fg = sigm_(glf[t]);
            float og = sigm_(glo[t]);
            cst = fg * cst + ig * gg;
            hp[t] = (f16)(og * tanh_(cst));
        }
        __syncthreads();                 // hp visible for next step
        xa0 = xn0; xa1 = xn1;
    }

    // fc: out[b][c] = h_T . fc_w[c] + fc_b[c]
    if (t < 128) {
        int c = t >> 6, j = t & 63;
        float p = (float)hp[2 * j] * fc_w[c * 128 + 2 * j]
                + (float)hp[2 * j + 1] * fc_w[c * 128 + 2 * j + 1];
        #pragma unroll
        for (int off = 32; off > 0; off >>= 1) p += __shfl_down(p, off, 64);
        if (j == 0) out[b * 2 + c] = p + fc_b[c];
    }
}

// ============================ launcher ============================
extern "C" void kernel_launch(void* const* d_in, const int* in_sizes, int n_in,
                              void* d_out, int out_size, void* d_ws, size_t ws_size,
                              hipStream_t stream) {
    const int*   x      = (const int*)d_in[0];
    const float* emb    = (const float*)d_in[1];
    const float* conv_w = (const float*)d_in[2];
    const float* conv_b = (const float*)d_in[3];
    const float* w_ih   = (const float*)d_in[4];
    const float* w_hh   = (const float*)d_in[5];
    const float* b_ih   = (const float*)d_in[6];
    const float* b_hh   = (const float*)d_in[7];
    const float* fc_w   = (const float*)d_in[8];
    const float* fc_b   = (const float*)d_in[9];
    float* out = (float*)d_out;

    char* ws = (char*)d_ws;
    bf16* bt     = (bf16*)(ws + WS_BT);
    bf16* w_ihb  = (bf16*)(ws + WS_WIHB);
    f16*  whh    = (f16*)(ws + WS_WHH);
    bf16* pooled = (bf16*)(ws + WS_POOLED);
    bf16* embb   = (bf16*)(ws + WS_EMB);
    f16*  xg     = (f16*)(ws + WS_XG);   // overlaps embb (emb dead after conv_pool)

    emb_cvt_k<<<2500, 256, 0, stream>>>(emb, embb);
    prep_small_k<<<544, 256, 0, stream>>>(conv_w, bt, w_ih, w_ihb, w_hh, whh);
    conv_pool_k<<<2048, 256, 0, stream>>>(x, embb, bt, conv_b, pooled);
    xg_gemm_k<<<256, 256, 0, stream>>>(pooled, w_ihb, b_ih, b_hh, xg);
    lstm_fc_k<<<64, 256, 0, stream>>>(xg, whh, fc_w, fc_b, out);
}

// Round 4
// 735.581 us; speedup vs baseline: 1.4079x; 1.0464x over previous
//
#include <hip/hip_runtime.h>
#include <stdint.h>
#include <stddef.h>

// CNNLSTM: embed -> conv1d(K=5) -> ReLU -> maxpool4 -> LSTM(T=1023,H=128) -> fc(2)
// Inputs: x int32; all float tensors float32. Output f32.
// Internals: bf16 MFMA for conv + input-projection GEMMs; f16 dot2 recurrence.

typedef __bf16 bf16;
typedef __bf16 bf16x8 __attribute__((ext_vector_type(8)));
typedef float  f32x4  __attribute__((ext_vector_type(4)));
typedef _Float16 f16;
typedef f16 f16x2 __attribute__((ext_vector_type(2)));
typedef f16 f16x4 __attribute__((ext_vector_type(4)));
typedef f16 f16x8 __attribute__((ext_vector_type(8)));

#define MFMA16(a, b, c) __builtin_amdgcn_mfma_f32_16x16x32_bf16((a), (b), (c), 0, 0, 0)

#if __has_builtin(__builtin_amdgcn_fdot2)
#define DOT2(a, b, c) __builtin_amdgcn_fdot2((a), (b), (c), false)
#else
#define DOT2(a, b, c) ((c) + (float)(a).x * (float)(b).x + (float)(a).y * (float)(b).y)
#endif

// Workgroup barrier that drains LDS (lgkm) but NOT in-flight global loads
// (__syncthreads emits s_waitcnt vmcnt(0) which puts HBM latency on the
// recurrence critical path; our cross-barrier vmem is read-only prefetch).
#define LGKM_BARRIER() asm volatile("s_waitcnt lgkmcnt(0)\ns_barrier" ::: "memory")

// ---------------- ws layout (bytes) ----------------
// xgT (written after conv_pool finishes) overlaps the dead emb_bf16 region.
#define WS_BT     0               // conv weights repacked [64][640] bf16 =    81,920
#define WS_WIHB   81920           // w_ih bf16 [512][64]                  =    65,536
#define WS_WHH    147456         // (unused this round, kept for layout)  =   131,072
#define WS_POOLED 278528          // pooled bf16 [64][1024][64]           = 8,388,608
#define WS_EMB    8667136         // emb bf16 [20000][128]                = 5,120,000
#define WS_XG     8667136         // xgT f16 [64][128][512][8]            = 67,108,864

// ============ prep A: emb f32 -> bf16 ============
__global__ void emb_cvt_k(const float* __restrict__ emb, bf16* __restrict__ embb) {
    int g = blockIdx.x * 256 + threadIdx.x;      // 640,000 threads x 4 elems
    f32x4 v = *(const f32x4*)(emb + g * 4);
    bf16* d = embb + g * 4;
    d[0] = (bf16)v[0]; d[1] = (bf16)v[1]; d[2] = (bf16)v[2]; d[3] = (bf16)v[3];
}

// ============ prep B: conv_w repack->bf16; w_ih->bf16 ============
__global__ void prep_small_k(const float* __restrict__ conv_w, bf16* __restrict__ bt,
                             const float* __restrict__ w_ih, bf16* __restrict__ w_ihb) {
    int g = blockIdx.x * 256 + threadIdx.x;
    if (g < 64 * 640) {
        int f = g / 640, kk = g - f * 640;
        int k = kk >> 7, e = kk & 127;
        bt[g] = (bf16)conv_w[(f * 128 + e) * 5 + k];
    } else {
        int h = g - 64 * 640;
        if (h < 512 * 64) w_ihb[h] = (bf16)w_ih[h];
    }
}

// ============ kernel 1: embed-gather + conv + ReLU + pool4 ============
__global__ __launch_bounds__(256, 2) void conv_pool_k(
    const int* __restrict__ x, const bf16* __restrict__ embb,
    const bf16* __restrict__ bt, const float* __restrict__ conv_b,
    bf16* __restrict__ pooled)
{
    __shared__ bf16 T[144 * 136];  // 136 = 128 + 8 pad
    const int b   = blockIdx.x >> 5;
    const int l0  = (blockIdx.x & 31) << 7;
    const int tid = threadIdx.x;
    const int ln  = tid & 63, w = tid >> 6;
    const int l15 = ln & 15, quad = ln >> 4;
    const int f   = w * 16 + l15;

    bf16x8 bfrag[20];
    #pragma unroll
    for (int kc = 0; kc < 20; ++kc) {
        uint4 v = *(const uint4*)(bt + f * 640 + kc * 32 + quad * 8);
        bfrag[kc] = __builtin_bit_cast(bf16x8, v);
    }
    const float cb = conv_b[f];

    #pragma unroll
    for (int p = 0; p < 9; ++p) {
        int r = p * 16 + (tid >> 4);
        int cg = tid & 15;
        int token = l0 + r; if (token > 4095) token = 4095;
        int idx = x[b * 4096 + token];
        uint4 v = *(const uint4*)(embb + idx * 128 + cg * 8);
        *(uint4*)(&T[r * 136 + cg * 8]) = v;
    }
    __syncthreads();

    f32x4 acc[8];
    #pragma unroll
    for (int tm = 0; tm < 8; ++tm) acc[tm] = (f32x4){0.f, 0.f, 0.f, 0.f};

    #pragma unroll
    for (int kc = 0; kc < 20; ++kc) {
        const int ktap = kc >> 2;
        const int ecol = (kc & 3) * 32 + quad * 8;
        #pragma unroll
        for (int tm = 0; tm < 8; ++tm) {
            int row = tm * 16 + l15 + ktap;
            bf16x8 a = *(const bf16x8*)(&T[row * 136 + ecol]);
            acc[tm] = MFMA16(a, bfrag[kc], acc[tm]);
        }
    }

    #pragma unroll
    for (int tm = 0; tm < 8; ++tm) {
        float mx = fmaxf(fmaxf(acc[tm][0], acc[tm][1]), fmaxf(acc[tm][2], acc[tm][3]));
        mx = fmaxf(mx + cb, 0.f);
        int t = (l0 >> 2) + tm * 4 + quad;
        if (t < 1023) pooled[(b * 1024 + t) * 64 + f] = (bf16)mx;
    }
}

// ============ kernel 2: xgT = pooled @ w_ih^T + (b_ih+b_hh), chunked f16 ============
// xgT[b][c][row][j] with t = c*8+j: LSTM reads 16B/thread, wave-coalesced.
__global__ __launch_bounds__(256, 2) void xg_gemm_k(
    const bf16* __restrict__ pooled, const bf16* __restrict__ w_ihb,
    const float* __restrict__ b_ih, const float* __restrict__ b_hh,
    f16* __restrict__ xg)
{
    __shared__ bf16 A[256 * 72];  // 72 = 64 + 8 pad
    const int m0  = blockIdx.x * 256;
    const int tid = threadIdx.x;
    const int ln  = tid & 63, w = tid >> 6;
    const int l15 = ln & 15, quad = ln >> 4;

    #pragma unroll
    for (int i = 0; i < 8; ++i) {
        int task = i * 256 + tid;
        int row = task >> 3, ch = task & 7;
        uint4 v = *(const uint4*)(pooled + (m0 + row) * 64 + ch * 8);
        *(uint4*)(&A[row * 72 + ch * 8]) = v;
    }
    __syncthreads();

    bf16x8 afrag[4][2];
    #pragma unroll
    for (int mt = 0; mt < 4; ++mt)
        #pragma unroll
        for (int kc = 0; kc < 2; ++kc)
            afrag[mt][kc] = *(const bf16x8*)(&A[((w * 4 + mt) * 16 + l15) * 72 + kc * 32 + quad * 8]);

    const int b_idx = m0 >> 10;
    const int tbase = m0 & 1023;

    for (int nt = 0; nt < 32; ++nt) {
        const int nn = nt * 16 + l15;
        uint4 v0 = *(const uint4*)(w_ihb + nn * 64 + quad * 8);
        uint4 v1 = *(const uint4*)(w_ihb + nn * 64 + 32 + quad * 8);
        bf16x8 bf0 = __builtin_bit_cast(bf16x8, v0);
        bf16x8 bf1 = __builtin_bit_cast(bf16x8, v1);
        const float bias = b_ih[nn] + b_hh[nn];
        #pragma unroll
        for (int mt = 0; mt < 4; ++mt) {
            f32x4 acc = (f32x4){0.f, 0.f, 0.f, 0.f};
            acc = MFMA16(afrag[mt][0], bf0, acc);
            acc = MFMA16(afrag[mt][1], bf1, acc);
            int t0 = tbase + (w * 4 + mt) * 16 + quad * 4;   // t0 % 4 == 0
            f16x4 sv = {(f16)(acc[0] + bias), (f16)(acc[1] + bias),
                        (f16)(acc[2] + bias), (f16)(acc[3] + bias)};
            size_t off = ((size_t)(b_idx * 128 + (t0 >> 3)) * 512 + nn) * 8 + (t0 & 7);
            *(f16x4*)(xg + off) = sv;   // 8B store, (t0&7) in {0,4}
        }
    }
}

// ============ kernel 3: LSTM recurrence + fc head ============
// 64 WGs x 256 threads. Thread t owns gate rows (t, 256+t):
//   t<128  -> (i, g) of unit t        t>=128 -> (f, o) of unit t-128
// Weights loaded as f32 and cvt->f16x2 in-kernel (pins them in VGPRs: a cvt
// chain is not rematerializable, unlike a const load). h f16[128] in LDS.
__device__ inline float sigm_(float v) {
    v = fminf(fmaxf(v, -30.f), 30.f);
    return __builtin_amdgcn_rcpf(1.f + __expf(-v));
}
__device__ inline float tanh_(float v) {
    v = fminf(fmaxf(v, -15.f), 15.f);
    return 1.f - 2.f * __builtin_amdgcn_rcpf(__expf(2.f * v) + 1.f);
}

__global__ __launch_bounds__(256, 1) void lstm_fc_k(
    const f16* __restrict__ xgT, const float* __restrict__ w_hh,
    const float* __restrict__ fc_w, const float* __restrict__ fc_b,
    float* __restrict__ out)
{
    __shared__ __align__(16) f16 hp[128];
    __shared__ __align__(16) float glfo[256];   // (fg, og) per unit
    const int b = blockIdx.x;
    const int t = threadIdx.x;
    const int r0 = t, r1 = 256 + t;

    f16x2 w0[64], w1[64];
    #pragma unroll
    for (int c = 0; c < 32; ++c) {
        f32x4 v = *(const f32x4*)(w_hh + r0 * 128 + c * 4);
        w0[c * 2 + 0] = (f16x2){(f16)v[0], (f16)v[1]};
        w0[c * 2 + 1] = (f16x2){(f16)v[2], (f16)v[3]};
    }
    #pragma unroll
    for (int c = 0; c < 32; ++c) {
        f32x4 v = *(const f32x4*)(w_hh + r1 * 128 + c * 4);
        w1[c * 2 + 0] = (f16x2){(f16)v[0], (f16)v[1]};
        w1[c * 2 + 1] = (f16x2){(f16)v[2], (f16)v[3]};
    }

    if (t < 128) hp[t] = (f16)0.f;
    float cst = 0.f;
    const f16* xp0 = xgT + (size_t)b * 524288 + r0 * 8;   // [b][c][row][8]
    const f16* xp1 = xgT + (size_t)b * 524288 + r1 * 8;
    f16x8 xb0 = *(const f16x8*)xp0;
    f16x8 xb1 = *(const f16x8*)xp1;
    LGKM_BARRIER();

    auto step = [&](float xa0, float xa1) {
        float a00 = 0.f, a01 = 0.f, a02 = 0.f, a03 = 0.f;
        float a10 = 0.f, a11 = 0.f, a12 = 0.f, a13 = 0.f;
        #pragma unroll
        for (int k = 0; k < 16; ++k) {
            f16x8 h8 = *(const f16x8*)(&hp[k * 8]);   // broadcast ds_read_b128
            f16x2 p0 = {h8[0], h8[1]}, p1 = {h8[2], h8[3]};
            f16x2 p2 = {h8[4], h8[5]}, p3 = {h8[6], h8[7]};
            a00 = DOT2(w0[k * 4 + 0], p0, a00); a01 = DOT2(w0[k * 4 + 1], p1, a01);
            a02 = DOT2(w0[k * 4 + 2], p2, a02); a03 = DOT2(w0[k * 4 + 3], p3, a03);
            a10 = DOT2(w1[k * 4 + 0], p0, a10); a11 = DOT2(w1[k * 4 + 1], p1, a11);
            a12 = DOT2(w1[k * 4 + 2], p2, a12); a13 = DOT2(w1[k * 4 + 3], p3, a13);
        }
        float acc0 = xa0 + ((a00 + a01) + (a02 + a03));
        float acc1 = xa1 + ((a10 + a11) + (a12 + a13));
        float v0, v1;
        if (t >= 128) {            // f,o: pre-activate and publish as a pair
            v0 = sigm_(acc0); v1 = sigm_(acc1);
            *(float2*)(&glfo[2 * (t - 128)]) = make_float2(v0, v1);
        } else {                   // i,g: pre-activate locally
            v0 = sigm_(acc0); v1 = tanh_(acc1);
        }
        LGKM_BARRIER();
        if (t < 128) {
            float2 fo = *(const float2*)(&glfo[2 * t]);
            cst = fo.x * cst + v0 * v1;
            hp[t] = (f16)(fo.y * tanh_(cst));
        }
        LGKM_BARRIER();
    };

    for (int c = 0; c < 127; ++c) {
        f16x8 nx0 = *(const f16x8*)(xp0 + (size_t)(c + 1) * 4096);  // prefetch next chunk
        f16x8 nx1 = *(const f16x8*)(xp1 + (size_t)(c + 1) * 4096);
        #pragma unroll
        for (int j = 0; j < 8; ++j) step((float)xb0[j], (float)xb1[j]);
        xb0 = nx0; xb1 = nx1;
    }
    #pragma unroll
    for (int j = 0; j < 7; ++j) step((float)xb0[j], (float)xb1[j]);  // steps 1016..1022

    // fc: out[b][c] = h_T . fc_w[c] + fc_b[c]
    if (t < 128) {
        int c = t >> 6, j = t & 63;
        float p = (float)hp[2 * j] * fc_w[c * 128 + 2 * j]
                + (float)hp[2 * j + 1] * fc_w[c * 128 + 2 * j + 1];
        #pragma unroll
        for (int off = 32; off > 0; off >>= 1) p += __shfl_down(p, off, 64);
        if (j == 0) out[b * 2 + c] = p + fc_b[c];
    }
}

// ============================ launcher ============================
extern "C" void kernel_launch(void* const* d_in, const int* in_sizes, int n_in,
                              void* d_out, int out_size, void* d_ws, size_t ws_size,
                              hipStream_t stream) {
    const int*   x      = (const int*)d_in[0];
    const float* emb    = (const float*)d_in[1];
    const float* conv_w = (const float*)d_in[2];
    const float* conv_b = (const float*)d_in[3];
    const float* w_ih   = (const float*)d_in[4];
    const float* w_hh   = (const float*)d_in[5];
    const float* b_ih   = (const float*)d_in[6];
    const float* b_hh   = (const float*)d_in[7];
    const float* fc_w   = (const float*)d_in[8];
    const float* fc_b   = (const float*)d_in[9];
    float* out = (float*)d_out;

    char* ws = (char*)d_ws;
    bf16* bt     = (bf16*)(ws + WS_BT);
    bf16* w_ihb  = (bf16*)(ws + WS_WIHB);
    bf16* pooled = (bf16*)(ws + WS_POOLED);
    bf16* embb   = (bf16*)(ws + WS_EMB);
    f16*  xg     = (f16*)(ws + WS_XG);   // overlaps embb (emb dead after conv_pool)

    emb_cvt_k<<<2500, 256, 0, stream>>>(emb, embb);
    prep_small_k<<<288, 256, 0, stream>>>(conv_w, bt, w_ih, w_ihb);
    conv_pool_k<<<2048, 256, 0, stream>>>(x, embb, bt, conv_b, pooled);
    xg_gemm_k<<<256, 256, 0, stream>>>(pooled, w_ihb, b_ih, b_hh, xg);
    lstm_fc_k<<<64, 256, 0, stream>>>(xg, w_hh, fc_w, fc_b, out);
}

// Round 5
// 735.109 us; speedup vs baseline: 1.4088x; 1.0006x over previous
//
#include <hip/hip_runtime.h>
#include <stdint.h>
#include <stddef.h>

// CNNLSTM: embed -> conv1d(K=5) -> ReLU -> maxpool4 -> LSTM(T=1023,H=128) -> fc(2)
// Inputs: x int32; all float tensors float32. Output f32.
// Internals: bf16 MFMA for conv + input-projection GEMMs; f16 dot2 recurrence.

typedef __bf16 bf16;
typedef __bf16 bf16x8 __attribute__((ext_vector_type(8)));
typedef float  f32x4  __attribute__((ext_vector_type(4)));
typedef _Float16 f16;
typedef f16 f16x2 __attribute__((ext_vector_type(2)));
typedef f16 f16x4 __attribute__((ext_vector_type(4)));
typedef f16 f16x8 __attribute__((ext_vector_type(8)));

#define MFMA16(a, b, c) __builtin_amdgcn_mfma_f32_16x16x32_bf16((a), (b), (c), 0, 0, 0)

#if __has_builtin(__builtin_amdgcn_fdot2)
#define DOT2(a, b, c) __builtin_amdgcn_fdot2((a), (b), (c), false)
#else
#define DOT2(a, b, c) ((c) + (float)(a).x * (float)(b).x + (float)(a).y * (float)(b).y)
#endif

// Barrier draining LDS (lgkm) but NOT in-flight global prefetch loads.
#define LGKM_BARRIER() asm volatile("s_waitcnt lgkmcnt(0)\ns_barrier" ::: "memory")

// ---------------- ws layout (bytes) ----------------
#define WS_BT     0               // conv weights repacked [64][640] bf16 =    81,920
#define WS_WIHB   81920           // w_ih bf16 [512][64]                  =    65,536
#define WS_POOLED 278528          // pooled bf16 [64][1024][64]           = 8,388,608
#define WS_EMB    8667136         // emb bf16 [20000][128]                = 5,120,000
#define WS_XG     8667136         // xgc f16 [64][128][128][4][8]         = 67,108,864
// (xgc overlaps emb_bf16: emb dead after conv_pool)

// ============ prep A: emb f32 -> bf16 ============
__global__ void emb_cvt_k(const float* __restrict__ emb, bf16* __restrict__ embb) {
    int g = blockIdx.x * 256 + threadIdx.x;
    f32x4 v = *(const f32x4*)(emb + g * 4);
    bf16* d = embb + g * 4;
    d[0] = (bf16)v[0]; d[1] = (bf16)v[1]; d[2] = (bf16)v[2]; d[3] = (bf16)v[3];
}

// ============ prep B: conv_w repack->bf16; w_ih->bf16 ============
__global__ void prep_small_k(const float* __restrict__ conv_w, bf16* __restrict__ bt,
                             const float* __restrict__ w_ih, bf16* __restrict__ w_ihb) {
    int g = blockIdx.x * 256 + threadIdx.x;
    if (g < 64 * 640) {
        int f = g / 640, kk = g - f * 640;
        int k = kk >> 7, e = kk & 127;
        bt[g] = (bf16)conv_w[(f * 128 + e) * 5 + k];
    } else {
        int h = g - 64 * 640;
        if (h < 512 * 64) w_ihb[h] = (bf16)w_ih[h];
    }
}

// ============ kernel 1: embed-gather + conv + ReLU + pool4 ============
__global__ __launch_bounds__(256, 2) void conv_pool_k(
    const int* __restrict__ x, const bf16* __restrict__ embb,
    const bf16* __restrict__ bt, const float* __restrict__ conv_b,
    bf16* __restrict__ pooled)
{
    __shared__ bf16 T[144 * 136];  // 136 = 128 + 8 pad
    const int b   = blockIdx.x >> 5;
    const int l0  = (blockIdx.x & 31) << 7;
    const int tid = threadIdx.x;
    const int ln  = tid & 63, w = tid >> 6;
    const int l15 = ln & 15, quad = ln >> 4;
    const int f   = w * 16 + l15;

    bf16x8 bfrag[20];
    #pragma unroll
    for (int kc = 0; kc < 20; ++kc) {
        uint4 v = *(const uint4*)(bt + f * 640 + kc * 32 + quad * 8);
        bfrag[kc] = __builtin_bit_cast(bf16x8, v);
    }
    const float cb = conv_b[f];

    #pragma unroll
    for (int p = 0; p < 9; ++p) {
        int r = p * 16 + (tid >> 4);
        int cg = tid & 15;
        int token = l0 + r; if (token > 4095) token = 4095;
        int idx = x[b * 4096 + token];
        uint4 v = *(const uint4*)(embb + idx * 128 + cg * 8);
        *(uint4*)(&T[r * 136 + cg * 8]) = v;
    }
    __syncthreads();

    f32x4 acc[8];
    #pragma unroll
    for (int tm = 0; tm < 8; ++tm) acc[tm] = (f32x4){0.f, 0.f, 0.f, 0.f};

    #pragma unroll
    for (int kc = 0; kc < 20; ++kc) {
        const int ktap = kc >> 2;
        const int ecol = (kc & 3) * 32 + quad * 8;
        #pragma unroll
        for (int tm = 0; tm < 8; ++tm) {
            int row = tm * 16 + l15 + ktap;
            bf16x8 a = *(const bf16x8*)(&T[row * 136 + ecol]);
            acc[tm] = MFMA16(a, bfrag[kc], acc[tm]);
        }
    }

    #pragma unroll
    for (int tm = 0; tm < 8; ++tm) {
        float mx = fmaxf(fmaxf(acc[tm][0], acc[tm][1]), fmaxf(acc[tm][2], acc[tm][3]));
        mx = fmaxf(mx + cb, 0.f);
        int t = (l0 >> 2) + tm * 4 + quad;
        if (t < 1023) pooled[(b * 1024 + t) * 64 + f] = (bf16)mx;
    }
}

// ============ kernel 2: xgc = pooled @ w_ih^T + (b_ih+b_hh), chunk-layout f16 ============
// xgc[b][c][unit][gate][j], t = c*8+j. LSTM thread reads 64 contiguous B/chunk.
__global__ __launch_bounds__(256, 2) void xg_gemm_k(
    const bf16* __restrict__ pooled, const bf16* __restrict__ w_ihb,
    const float* __restrict__ b_ih, const float* __restrict__ b_hh,
    f16* __restrict__ xg)
{
    __shared__ bf16 A[256 * 72];  // 72 = 64 + 8 pad
    const int m0  = blockIdx.x * 256;
    const int tid = threadIdx.x;
    const int ln  = tid & 63, w = tid >> 6;
    const int l15 = ln & 15, quad = ln >> 4;

    #pragma unroll
    for (int i = 0; i < 8; ++i) {
        int task = i * 256 + tid;
        int row = task >> 3, ch = task & 7;
        uint4 v = *(const uint4*)(pooled + (m0 + row) * 64 + ch * 8);
        *(uint4*)(&A[row * 72 + ch * 8]) = v;
    }
    __syncthreads();

    bf16x8 afrag[4][2];
    #pragma unroll
    for (int mt = 0; mt < 4; ++mt)
        #pragma unroll
        for (int kc = 0; kc < 2; ++kc)
            afrag[mt][kc] = *(const bf16x8*)(&A[((w * 4 + mt) * 16 + l15) * 72 + kc * 32 + quad * 8]);

    const int b_idx = m0 >> 10;
    const int tbase = m0 & 1023;

    for (int nt = 0; nt < 32; ++nt) {
        const int nn = nt * 16 + l15;
        uint4 v0 = *(const uint4*)(w_ihb + nn * 64 + quad * 8);
        uint4 v1 = *(const uint4*)(w_ihb + nn * 64 + 32 + quad * 8);
        bf16x8 bf0 = __builtin_bit_cast(bf16x8, v0);
        bf16x8 bf1 = __builtin_bit_cast(bf16x8, v1);
        const float bias = b_ih[nn] + b_hh[nn];
        const int unit = nn & 127, gate = nn >> 7;
        #pragma unroll
        for (int mt = 0; mt < 4; ++mt) {
            f32x4 acc = (f32x4){0.f, 0.f, 0.f, 0.f};
            acc = MFMA16(afrag[mt][0], bf0, acc);
            acc = MFMA16(afrag[mt][1], bf1, acc);
            int t0 = tbase + (w * 4 + mt) * 16 + quad * 4;   // t0 % 4 == 0
            f16x4 sv = {(f16)(acc[0] + bias), (f16)(acc[1] + bias),
                        (f16)(acc[2] + bias), (f16)(acc[3] + bias)};
            size_t off = (((size_t)(b_idx * 128 + (t0 >> 3)) * 128 + unit) * 4 + gate) * 8 + (t0 & 7);
            *(f16x4*)(xg + off) = sv;   // 8B store, (t0&7) in {0,4}
        }
    }
}

// ============ kernel 3: LSTM recurrence + fc head ============
// 64 WGs x 256 threads (4 waves). Thread pair (2u, 2u+1) owns unit u:
// each thread holds all 4 gate rows (i,f,g,o) of unit u over half of K
// (kh = t&1 -> K in [64*kh, 64*kh+64)). Partials merged via shfl_xor(1);
// cell update is fully local to the even lane. h double-buffered in LDS ->
// ONE lgkm barrier per step. Weights pinned in VGPRs via asm "+v" (defeats
// the invariant-load rematerialization seen in R3/R4: VGPR_Count was 132 <
// the 160+ needed, i.e. weights were re-fetched from L2 every step).
__device__ inline float sigm_(float v) {
    v = fminf(fmaxf(v, -30.f), 30.f);
    return __builtin_amdgcn_rcpf(1.f + __expf(-v));
}
__device__ inline float tanh_(float v) {
    v = fminf(fmaxf(v, -15.f), 15.f);
    return 1.f - 2.f * __builtin_amdgcn_rcpf(__expf(2.f * v) + 1.f);
}

__global__ __launch_bounds__(256, 1) void lstm_fc_k(
    const f16* __restrict__ xgc, const float* __restrict__ w_hh,
    const float* __restrict__ fc_w, const float* __restrict__ fc_b,
    float* __restrict__ out)
{
    __shared__ __align__(16) f16 hp[2][128];
    const int b  = blockIdx.x;
    const int t  = threadIdx.x;   // 0..255
    const int u  = t >> 1;        // unit 0..127
    const int kh = t & 1;         // K-half

    // 4 gate rows x 64 K = 256 f16 = 128 f16x2 VGPRs
    f16x2 wv[4][32];
    #pragma unroll
    for (int g = 0; g < 4; ++g) {
        const float* wr = w_hh + (g * 128 + u) * 128 + kh * 64;
        #pragma unroll
        for (int c = 0; c < 16; ++c) {
            f32x4 v = *(const f32x4*)(wr + c * 4);
            wv[g][c * 2 + 0] = (f16x2){(f16)v[0], (f16)v[1]};
            wv[g][c * 2 + 1] = (f16x2){(f16)v[2], (f16)v[3]};
        }
    }
    #pragma unroll
    for (int g = 0; g < 4; ++g)
        #pragma unroll
        for (int i = 0; i < 32; ++i) {
            uint32_t r = __builtin_bit_cast(uint32_t, wv[g][i]);
            asm volatile("" : "+v"(r));           // pin: not remat-able
            wv[g][i] = __builtin_bit_cast(f16x2, r);
        }

    const f16* xb = xgc + (size_t)b * 524288 + (size_t)u * 32;  // [b][c][u][4][8]
    f16x8 xq[4], nxq[4];
    #pragma unroll
    for (int g = 0; g < 4; ++g) xq[g] = *(const f16x8*)(xb + g * 8);

    if (t < 128) hp[0][t] = (f16)0.f;
    float cst = 0.f;
    int p = 0;
    LGKM_BARRIER();

    auto step = [&](int j) {
        const f16* hsrc = &hp[p][kh * 64];
        float ai0 = 0.f, ai1 = 0.f, af0 = 0.f, af1 = 0.f;
        float ag0 = 0.f, ag1 = 0.f, ao0 = 0.f, ao1 = 0.f;
        #pragma unroll
        for (int c = 0; c < 8; ++c) {
            f16x8 h8 = *(const f16x8*)(hsrc + c * 8);   // 2-addr broadcast read
            f16x2 p0 = {h8[0], h8[1]}, p1 = {h8[2], h8[3]};
            f16x2 p2 = {h8[4], h8[5]}, p3 = {h8[6], h8[7]};
            ai0 = DOT2(wv[0][c*4+0], p0, ai0); ai1 = DOT2(wv[0][c*4+1], p1, ai1);
            ai0 = DOT2(wv[0][c*4+2], p2, ai0); ai1 = DOT2(wv[0][c*4+3], p3, ai1);
            af0 = DOT2(wv[1][c*4+0], p0, af0); af1 = DOT2(wv[1][c*4+1], p1, af1);
            af0 = DOT2(wv[1][c*4+2], p2, af0); af1 = DOT2(wv[1][c*4+3], p3, af1);
            ag0 = DOT2(wv[2][c*4+0], p0, ag0); ag1 = DOT2(wv[2][c*4+1], p1, ag1);
            ag0 = DOT2(wv[2][c*4+2], p2, ag0); ag1 = DOT2(wv[2][c*4+3], p3, ag1);
            ao0 = DOT2(wv[3][c*4+0], p0, ao0); ao1 = DOT2(wv[3][c*4+1], p1, ao1);
            ao0 = DOT2(wv[3][c*4+2], p2, ao0); ao1 = DOT2(wv[3][c*4+3], p3, ao1);
        }
        float ai = ai0 + ai1, af = af0 + af1, ag = ag0 + ag1, ao = ao0 + ao1;
        ai += __shfl_xor(ai, 1, 64);
        af += __shfl_xor(af, 1, 64);
        ag += __shfl_xor(ag, 1, 64);
        ao += __shfl_xor(ao, 1, 64);
        if (kh == 0) {
            float ig = sigm_(ai + (float)xq[0][j]);
            float fg = sigm_(af + (float)xq[1][j]);
            float gg = tanh_(ag + (float)xq[2][j]);
            float og = sigm_(ao + (float)xq[3][j]);
            cst = fg * cst + ig * gg;
            hp[p ^ 1][u] = (f16)(og * tanh_(cst));
        }
        p ^= 1;
        LGKM_BARRIER();
    };

    for (int c = 0; c < 127; ++c) {
        #pragma unroll
        for (int g = 0; g < 4; ++g)      // prefetch next chunk (not drained by barrier)
            nxq[g] = *(const f16x8*)(xb + (size_t)(c + 1) * 4096 + g * 8);
        #pragma unroll
        for (int j = 0; j < 8; ++j) step(j);
        #pragma unroll
        for (int g = 0; g < 4; ++g) xq[g] = nxq[g];
    }
    #pragma unroll
    for (int j = 0; j < 7; ++j) step(j);   // steps 1016..1022

    // fc: out[b][c] = h_T . fc_w[c] + fc_b[c]   (final h in hp[p])
    if (t < 128) {
        int c2 = t >> 6, j2 = t & 63;
        float pr = (float)hp[p][2 * j2] * fc_w[c2 * 128 + 2 * j2]
                 + (float)hp[p][2 * j2 + 1] * fc_w[c2 * 128 + 2 * j2 + 1];
        #pragma unroll
        for (int off = 32; off > 0; off >>= 1) pr += __shfl_down(pr, off, 64);
        if (j2 == 0) out[b * 2 + c2] = pr + fc_b[c2];
    }
}

// ============================ launcher ============================
extern "C" void kernel_launch(void* const* d_in, const int* in_sizes, int n_in,
                              void* d_out, int out_size, void* d_ws, size_t ws_size,
                              hipStream_t stream) {
    const int*   x      = (const int*)d_in[0];
    const float* emb    = (const float*)d_in[1];
    const float* conv_w = (const float*)d_in[2];
    const float* conv_b = (const float*)d_in[3];
    const float* w_ih   = (const float*)d_in[4];
    const float* w_hh   = (const float*)d_in[5];
    const float* b_ih   = (const float*)d_in[6];
    const float* b_hh   = (const float*)d_in[7];
    const float* fc_w   = (const float*)d_in[8];
    const float* fc_b   = (const float*)d_in[9];
    float* out = (float*)d_out;

    char* ws = (char*)d_ws;
    bf16* bt     = (bf16*)(ws + WS_BT);
    bf16* w_ihb  = (bf16*)(ws + WS_WIHB);
    bf16* pooled = (bf16*)(ws + WS_POOLED);
    bf16* embb   = (bf16*)(ws + WS_EMB);
    f16*  xg     = (f16*)(ws + WS_XG);   // overlaps embb (emb dead after conv_pool)

    emb_cvt_k<<<2500, 256, 0, stream>>>(emb, embb);
    prep_small_k<<<288, 256, 0, stream>>>(conv_w, bt, w_ih, w_ihb);
    conv_pool_k<<<2048, 256, 0, stream>>>(x, embb, bt, conv_b, pooled);
    xg_gemm_k<<<256, 256, 0, stream>>>(pooled, w_ihb, b_ih, b_hh, xg);
    lstm_fc_k<<<64, 256, 0, stream>>>(xg, w_hh, fc_w, fc_b, out);
}

// Round 6
// 731.766 us; speedup vs baseline: 1.4152x; 1.0046x over previous
//
#include <hip/hip_runtime.h>
#include <stdint.h>
#include <stddef.h>

// CNNLSTM: embed -> conv1d(K=5) -> ReLU -> maxpool4 -> LSTM(T=1023,H=128) -> fc(2)
// Inputs: x int32; all float tensors float32. Output f32.
// Internals: bf16 MFMA for conv + input-projection GEMMs; f16 dot2 recurrence.

typedef __bf16 bf16;
typedef __bf16 bf16x8 __attribute__((ext_vector_type(8)));
typedef float  f32x4  __attribute__((ext_vector_type(4)));
typedef _Float16 f16;
typedef f16 f16x2 __attribute__((ext_vector_type(2)));
typedef f16 f16x4 __attribute__((ext_vector_type(4)));
typedef f16 f16x8 __attribute__((ext_vector_type(8)));

#define MFMA16(a, b, c) __builtin_amdgcn_mfma_f32_16x16x32_bf16((a), (b), (c), 0, 0, 0)

#if __has_builtin(__builtin_amdgcn_fdot2)
#define DOT2(a, b, c) __builtin_amdgcn_fdot2((a), (b), (c), false)
#else
#define DOT2(a, b, c) ((c) + (float)(a).x * (float)(b).x + (float)(a).y * (float)(b).y)
#endif

// Barrier draining LDS (lgkm) but NOT in-flight global prefetch loads.
#define LGKM_BARRIER() asm volatile("s_waitcnt lgkmcnt(0)\ns_barrier" ::: "memory")

// ---------------- ws layout (bytes) ----------------
#define WS_BT     0               // conv weights repacked [64][640] bf16 =    81,920
#define WS_WIHB   81920           // w_ih bf16 [512][64]                  =    65,536
#define WS_POOLED 278528          // pooled bf16 [64][1024][64]           = 8,388,608
#define WS_EMB    8667136         // emb bf16 [20000][128]                = 5,120,000
#define WS_XG     8667136         // xgc f16 [64][128][128][4][8]         = 67,108,864
// (xgc overlaps emb_bf16: emb dead after conv_pool)

// ============ prep A: emb f32 -> bf16 ============
__global__ void emb_cvt_k(const float* __restrict__ emb, bf16* __restrict__ embb) {
    int g = blockIdx.x * 256 + threadIdx.x;
    f32x4 v = *(const f32x4*)(emb + g * 4);
    bf16* d = embb + g * 4;
    d[0] = (bf16)v[0]; d[1] = (bf16)v[1]; d[2] = (bf16)v[2]; d[3] = (bf16)v[3];
}

// ============ prep B: conv_w repack->bf16; w_ih->bf16 ============
__global__ void prep_small_k(const float* __restrict__ conv_w, bf16* __restrict__ bt,
                             const float* __restrict__ w_ih, bf16* __restrict__ w_ihb) {
    int g = blockIdx.x * 256 + threadIdx.x;
    if (g < 64 * 640) {
        int f = g / 640, kk = g - f * 640;
        int k = kk >> 7, e = kk & 127;
        bt[g] = (bf16)conv_w[(f * 128 + e) * 5 + k];
    } else {
        int h = g - 64 * 640;
        if (h < 512 * 64) w_ihb[h] = (bf16)w_ih[h];
    }
}

// ============ kernel 1: embed-gather + conv + ReLU + pool4 ============
__global__ __launch_bounds__(256, 2) void conv_pool_k(
    const int* __restrict__ x, const bf16* __restrict__ embb,
    const bf16* __restrict__ bt, const float* __restrict__ conv_b,
    bf16* __restrict__ pooled)
{
    __shared__ bf16 T[144 * 136];  // 136 = 128 + 8 pad
    const int b   = blockIdx.x >> 5;
    const int l0  = (blockIdx.x & 31) << 7;
    const int tid = threadIdx.x;
    const int ln  = tid & 63, w = tid >> 6;
    const int l15 = ln & 15, quad = ln >> 4;
    const int f   = w * 16 + l15;

    bf16x8 bfrag[20];
    #pragma unroll
    for (int kc = 0; kc < 20; ++kc) {
        uint4 v = *(const uint4*)(bt + f * 640 + kc * 32 + quad * 8);
        bfrag[kc] = __builtin_bit_cast(bf16x8, v);
    }
    const float cb = conv_b[f];

    #pragma unroll
    for (int p = 0; p < 9; ++p) {
        int r = p * 16 + (tid >> 4);
        int cg = tid & 15;
        int token = l0 + r; if (token > 4095) token = 4095;
        int idx = x[b * 4096 + token];
        uint4 v = *(const uint4*)(embb + idx * 128 + cg * 8);
        *(uint4*)(&T[r * 136 + cg * 8]) = v;
    }
    __syncthreads();

    f32x4 acc[8];
    #pragma unroll
    for (int tm = 0; tm < 8; ++tm) acc[tm] = (f32x4){0.f, 0.f, 0.f, 0.f};

    #pragma unroll
    for (int kc = 0; kc < 20; ++kc) {
        const int ktap = kc >> 2;
        const int ecol = (kc & 3) * 32 + quad * 8;
        #pragma unroll
        for (int tm = 0; tm < 8; ++tm) {
            int row = tm * 16 + l15 + ktap;
            bf16x8 a = *(const bf16x8*)(&T[row * 136 + ecol]);
            acc[tm] = MFMA16(a, bfrag[kc], acc[tm]);
        }
    }

    #pragma unroll
    for (int tm = 0; tm < 8; ++tm) {
        float mx = fmaxf(fmaxf(acc[tm][0], acc[tm][1]), fmaxf(acc[tm][2], acc[tm][3]));
        mx = fmaxf(mx + cb, 0.f);
        int t = (l0 >> 2) + tm * 4 + quad;
        if (t < 1023) pooled[(b * 1024 + t) * 64 + f] = (bf16)mx;
    }
}

// ============ kernel 2: xgc = pooled @ w_ih^T + (b_ih+b_hh), chunk-layout f16 ============
// xgc[b][c][unit][gate][j], t = c*8+j. LSTM thread reads 64 contiguous B/chunk.
__global__ __launch_bounds__(256, 2) void xg_gemm_k(
    const bf16* __restrict__ pooled, const bf16* __restrict__ w_ihb,
    const float* __restrict__ b_ih, const float* __restrict__ b_hh,
    f16* __restrict__ xg)
{
    __shared__ bf16 A[256 * 72];  // 72 = 64 + 8 pad
    const int m0  = blockIdx.x * 256;
    const int tid = threadIdx.x;
    const int ln  = tid & 63, w = tid >> 6;
    const int l15 = ln & 15, quad = ln >> 4;

    #pragma unroll
    for (int i = 0; i < 8; ++i) {
        int task = i * 256 + tid;
        int row = task >> 3, ch = task & 7;
        uint4 v = *(const uint4*)(pooled + (m0 + row) * 64 + ch * 8);
        *(uint4*)(&A[row * 72 + ch * 8]) = v;
    }
    __syncthreads();

    bf16x8 afrag[4][2];
    #pragma unroll
    for (int mt = 0; mt < 4; ++mt)
        #pragma unroll
        for (int kc = 0; kc < 2; ++kc)
            afrag[mt][kc] = *(const bf16x8*)(&A[((w * 4 + mt) * 16 + l15) * 72 + kc * 32 + quad * 8]);

    const int b_idx = m0 >> 10;
    const int tbase = m0 & 1023;

    for (int nt = 0; nt < 32; ++nt) {
        const int nn = nt * 16 + l15;
        uint4 v0 = *(const uint4*)(w_ihb + nn * 64 + quad * 8);
        uint4 v1 = *(const uint4*)(w_ihb + nn * 64 + 32 + quad * 8);
        bf16x8 bf0 = __builtin_bit_cast(bf16x8, v0);
        bf16x8 bf1 = __builtin_bit_cast(bf16x8, v1);
        const float bias = b_ih[nn] + b_hh[nn];
        const int unit = nn & 127, gate = nn >> 7;
        #pragma unroll
        for (int mt = 0; mt < 4; ++mt) {
            f32x4 acc = (f32x4){0.f, 0.f, 0.f, 0.f};
            acc = MFMA16(afrag[mt][0], bf0, acc);
            acc = MFMA16(afrag[mt][1], bf1, acc);
            int t0 = tbase + (w * 4 + mt) * 16 + quad * 4;   // t0 % 4 == 0
            f16x4 sv = {(f16)(acc[0] + bias), (f16)(acc[1] + bias),
                        (f16)(acc[2] + bias), (f16)(acc[3] + bias)};
            size_t off = (((size_t)(b_idx * 128 + (t0 >> 3)) * 128 + unit) * 4 + gate) * 8 + (t0 & 7);
            *(f16x4*)(xg + off) = sv;   // 8B store, (t0&7) in {0,4}
        }
    }
}

// ============ kernel 3: LSTM recurrence + fc head ============
// 64 WGs x 256 threads (4 waves = 1 wave/EU; only 64 of 256 CUs used).
// Thread pair (2u, 2u+1) owns unit u: all 4 gate rows over half of K.
// Partials merged via shfl_xor(1); cell update local to even lane; h double-
// buffered in LDS -> one lgkm barrier/step.
// amdgpu_waves_per_eu(1,1): R5 showed VGPR_Count=128 (the 4-waves/EU step) --
// the allocator SPILLED the asm-pinned weights to scratch to hit an occupancy
// target that is physically irrelevant here (1 wave/EU regardless). max=1
// removes that target so the ~160 live regs stay resident.
__device__ inline float sigm_(float v) {
    v = fminf(fmaxf(v, -30.f), 30.f);
    return __builtin_amdgcn_rcpf(1.f + __expf(-v));
}
__device__ inline float tanh_(float v) {
    v = fminf(fmaxf(v, -15.f), 15.f);
    return 1.f - 2.f * __builtin_amdgcn_rcpf(__expf(2.f * v) + 1.f);
}

__global__ __launch_bounds__(256, 1) __attribute__((amdgpu_waves_per_eu(1, 1)))
void lstm_fc_k(
    const f16* __restrict__ xgc, const float* __restrict__ w_hh,
    const float* __restrict__ fc_w, const float* __restrict__ fc_b,
    float* __restrict__ out)
{
    __shared__ __align__(16) f16 hp[2][128];
    const int b  = blockIdx.x;
    const int t  = threadIdx.x;   // 0..255
    const int u  = t >> 1;        // unit 0..127
    const int kh = t & 1;         // K-half

    // 4 gate rows x 64 K = 256 f16 = 128 f16x2 VGPRs
    f16x2 wv[4][32];
    #pragma unroll
    for (int g = 0; g < 4; ++g) {
        const float* wr = w_hh + (g * 128 + u) * 128 + kh * 64;
        #pragma unroll
        for (int c = 0; c < 16; ++c) {
            f32x4 v = *(const f32x4*)(wr + c * 4);
            wv[g][c * 2 + 0] = (f16x2){(f16)v[0], (f16)v[1]};
            wv[g][c * 2 + 1] = (f16x2){(f16)v[2], (f16)v[3]};
        }
    }
    #pragma unroll
    for (int g = 0; g < 4; ++g)
        #pragma unroll
        for (int i = 0; i < 32; ++i) {
            uint32_t r = __builtin_bit_cast(uint32_t, wv[g][i]);
            asm volatile("" : "+v"(r));           // pin: not remat-able
            wv[g][i] = __builtin_bit_cast(f16x2, r);
        }

    const f16* xb = xgc + (size_t)b * 524288 + (size_t)u * 32;  // [b][c][u][4][8]
    f16x8 xq[4], nxq[4];
    #pragma unroll
    for (int g = 0; g < 4; ++g) xq[g] = *(const f16x8*)(xb + g * 8);

    if (t < 128) hp[0][t] = (f16)0.f;
    float cst = 0.f;
    int p = 0;
    LGKM_BARRIER();

    auto step = [&](int j) {
        const f16* hsrc = &hp[p][kh * 64];
        float ai0 = 0.f, ai1 = 0.f, af0 = 0.f, af1 = 0.f;
        float ag0 = 0.f, ag1 = 0.f, ao0 = 0.f, ao1 = 0.f;
        #pragma unroll
        for (int c = 0; c < 8; ++c) {
            f16x8 h8 = *(const f16x8*)(hsrc + c * 8);   // 2-addr broadcast read
            f16x2 p0 = {h8[0], h8[1]}, p1 = {h8[2], h8[3]};
            f16x2 p2 = {h8[4], h8[5]}, p3 = {h8[6], h8[7]};
            ai0 = DOT2(wv[0][c*4+0], p0, ai0); ai1 = DOT2(wv[0][c*4+1], p1, ai1);
            ai0 = DOT2(wv[0][c*4+2], p2, ai0); ai1 = DOT2(wv[0][c*4+3], p3, ai1);
            af0 = DOT2(wv[1][c*4+0], p0, af0); af1 = DOT2(wv[1][c*4+1], p1, af1);
            af0 = DOT2(wv[1][c*4+2], p2, af0); af1 = DOT2(wv[1][c*4+3], p3, af1);
            ag0 = DOT2(wv[2][c*4+0], p0, ag0); ag1 = DOT2(wv[2][c*4+1], p1, ag1);
            ag0 = DOT2(wv[2][c*4+2], p2, ag0); ag1 = DOT2(wv[2][c*4+3], p3, ag1);
            ao0 = DOT2(wv[3][c*4+0], p0, ao0); ao1 = DOT2(wv[3][c*4+1], p1, ao1);
            ao0 = DOT2(wv[3][c*4+2], p2, ao0); ao1 = DOT2(wv[3][c*4+3], p3, ao1);
        }
        float ai = ai0 + ai1, af = af0 + af1, ag = ag0 + ag1, ao = ao0 + ao1;
        ai += __shfl_xor(ai, 1, 64);
        af += __shfl_xor(af, 1, 64);
        ag += __shfl_xor(ag, 1, 64);
        ao += __shfl_xor(ao, 1, 64);
        if (kh == 0) {
            float ig = sigm_(ai + (float)xq[0][j]);
            float fg = sigm_(af + (float)xq[1][j]);
            float gg = tanh_(ag + (float)xq[2][j]);
            float og = sigm_(ao + (float)xq[3][j]);
            cst = fg * cst + ig * gg;
            hp[p ^ 1][u] = (f16)(og * tanh_(cst));
        }
        p ^= 1;
        LGKM_BARRIER();
    };

    for (int c = 0; c < 127; ++c) {
        #pragma unroll
        for (int g = 0; g < 4; ++g)      // prefetch next chunk (not drained by barrier)
            nxq[g] = *(const f16x8*)(xb + (size_t)(c + 1) * 4096 + g * 8);
        #pragma unroll
        for (int j = 0; j < 8; ++j) step(j);
        #pragma unroll
        for (int g = 0; g < 4; ++g) xq[g] = nxq[g];
    }
    #pragma unroll
    for (int j = 0; j < 7; ++j) step(j);   // steps 1016..1022

    // fc: out[b][c] = h_T . fc_w[c] + fc_b[c]   (final h in hp[p])
    if (t < 128) {
        int c2 = t >> 6, j2 = t & 63;
        float pr = (float)hp[p][2 * j2] * fc_w[c2 * 128 + 2 * j2]
                 + (float)hp[p][2 * j2 + 1] * fc_w[c2 * 128 + 2 * j2 + 1];
        #pragma unroll
        for (int off = 32; off > 0; off >>= 1) pr += __shfl_down(pr, off, 64);
        if (j2 == 0) out[b * 2 + c2] = pr + fc_b[c2];
    }
}

// ============================ launcher ============================
extern "C" void kernel_launch(void* const* d_in, const int* in_sizes, int n_in,
                              void* d_out, int out_size, void* d_ws, size_t ws_size,
                              hipStream_t stream) {
    const int*   x      = (const int*)d_in[0];
    const float* emb    = (const float*)d_in[1];
    const float* conv_w = (const float*)d_in[2];
    const float* conv_b = (const float*)d_in[3];
    const float* w_ih   = (const float*)d_in[4];
    const float* w_hh   = (const float*)d_in[5];
    const float* b_ih   = (const float*)d_in[6];
    const float* b_hh   = (const float*)d_in[7];
    const float* fc_w   = (const float*)d_in[8];
    const float* fc_b   = (const float*)d_in[9];
    float* out = (float*)d_out;

    char* ws = (char*)d_ws;
    bf16* bt     = (bf16*)(ws + WS_BT);
    bf16* w_ihb  = (bf16*)(ws + WS_WIHB);
    bf16* pooled = (bf16*)(ws + WS_POOLED);
    bf16* embb   = (bf16*)(ws + WS_EMB);
    f16*  xg     = (f16*)(ws + WS_XG);   // overlaps embb (emb dead after conv_pool)

    emb_cvt_k<<<2500, 256, 0, stream>>>(emb, embb);
    prep_small_k<<<288, 256, 0, stream>>>(conv_w, bt, w_ih, w_ihb);
    conv_pool_k<<<2048, 256, 0, stream>>>(x, embb, bt, conv_b, pooled);
    xg_gemm_k<<<256, 256, 0, stream>>>(pooled, w_ihb, b_ih, b_hh, xg);
    lstm_fc_k<<<64, 256, 0, stream>>>(xg, w_hh, fc_w, fc_b, out);
}